// Round 2
// 290.076 us; speedup vs baseline: 1.2671x; 1.2671x over previous
//
#include <hip/hip_runtime.h>
#include <stdint.h>

// NCA: B=8, C=16, H=W=128, hidden=128, 8 steps.
// ws: [0,8MB) midA, [8MB,16MB) midB, [+512KB) mid3c, [+128KB) pre,
//     [+2MB) mask bits, [+40KB) f16 split weight fragments. ~18.7 MB.

#define BATCH 8
#define CH 16
#define HT 128
#define WD 128
#define HIDN 128
#define PLANE (HT*WD)
#define IMG (CH*PLANE)
#define NELEM (BATCH*IMG)
#define NPIX (BATCH*PLANE)
#define WORDS_PER_STEP (NELEM/32)
#define NSTEPS 8

// ---- MFMA step kernel geometry ----
// Per-wave LDS region (no cross-wave sharing -> no __syncthreads anywhere):
//   P (perceived, f16 hi/lo): 16 rows x 72 f16 x 2B = 2304 B per array
//   H (hidden, f16 hi/lo):    16 rows x 136 f16 x 2B = 4352 B per array (overlays P)
//   DX (fp32 transpose):      16 x 17 x 4B = 1088 B
#define PSTR 72      // 144B rows: b128 A-frag reads perfectly tile 32 banks
#define HSTR 136     // 272B rows: same property for GEMM2 A-frags
#define DSTR 17
#define POFF_LO 2304
#define HOFF_LO 4352
#define DXOFF   8704
#define WREG    9792 // bytes per wave region; 4 waves -> 39168 B/block -> 4 blocks/CU

typedef _Float16 f16x8 __attribute__((ext_vector_type(8)));
typedef float    f32x4 __attribute__((ext_vector_type(4)));

struct Keys { unsigned k[2*NSTEPS]; };

__host__ __device__ __forceinline__ unsigned rotl32u(unsigned v, int r) {
  return (v << r) | (v >> (32 - r));
}

// JAX threefry2x32 (20 rounds).
__host__ __device__ __forceinline__ void tf2x32(unsigned k0, unsigned k1,
                                                unsigned c0, unsigned c1,
                                                unsigned &o0, unsigned &o1) {
  const unsigned ks2 = k0 ^ k1 ^ 0x1BD11BDAu;
  unsigned x0 = c0 + k0, x1 = c1 + k1;
  x0 += x1; x1 = rotl32u(x1, 13); x1 ^= x0;
  x0 += x1; x1 = rotl32u(x1, 15); x1 ^= x0;
  x0 += x1; x1 = rotl32u(x1, 26); x1 ^= x0;
  x0 += x1; x1 = rotl32u(x1,  6); x1 ^= x0;
  x0 += k1; x1 += ks2 + 1u;
  x0 += x1; x1 = rotl32u(x1, 17); x1 ^= x0;
  x0 += x1; x1 = rotl32u(x1, 29); x1 ^= x0;
  x0 += x1; x1 = rotl32u(x1, 16); x1 ^= x0;
  x0 += x1; x1 = rotl32u(x1, 24); x1 ^= x0;
  x0 += ks2; x1 += k0 + 2u;
  x0 += x1; x1 = rotl32u(x1, 13); x1 ^= x0;
  x0 += x1; x1 = rotl32u(x1, 15); x1 ^= x0;
  x0 += x1; x1 = rotl32u(x1, 26); x1 ^= x0;
  x0 += x1; x1 = rotl32u(x1,  6); x1 ^= x0;
  x0 += k0; x1 += k1 + 3u;
  x0 += x1; x1 = rotl32u(x1, 17); x1 ^= x0;
  x0 += x1; x1 = rotl32u(x1, 29); x1 ^= x0;
  x0 += x1; x1 = rotl32u(x1, 16); x1 ^= x0;
  x0 += x1; x1 = rotl32u(x1, 24); x1 ^= x0;
  x0 += k1; x1 += ks2 + 4u;
  x0 += x1; x1 = rotl32u(x1, 13); x1 ^= x0;
  x0 += x1; x1 = rotl32u(x1, 15); x1 ^= x0;
  x0 += x1; x1 = rotl32u(x1, 26); x1 ^= x0;
  x0 += x1; x1 = rotl32u(x1,  6); x1 ^= x0;
  x0 += ks2; x1 += k0 + 5u;
  o0 = x0; o1 = x1;
}

// UNCHANGED from baseline: the passing absmax depends on these exact bits.
__global__ __launch_bounds__(256) void mask_kernel(unsigned* __restrict__ mask,
                                                   Keys keys) {
  unsigned t = blockIdx.x * 256u + threadIdx.x;
  unsigned step = t >> 16;
  unsigned k0 = keys.k[2*step], k1 = keys.k[2*step + 1];
  unsigned base = (t & 65535u) << 5;
  unsigned word = 0u;
  #pragma unroll 4
  for (int i = 0; i < 32; ++i) {
    unsigned b1x, b2x;
    tf2x32(k0, k1, 0u, base + (unsigned)i, b1x, b2x);
    unsigned bits = b1x ^ b2x;
    word |= (((bits >> 9) != 0u) ? 1u : 0u) << i;
  }
  mask[t] = word;
}

// Split each weight into f16 hi + f16 lo and pre-pack in MFMA B-fragment
// order so the step kernel loads one dwordx4 per lane per fragment.
// w1f layout: [kt(2)][nt(8)][lane(64)][i(8)] halves, k = kt*32+(lane>>4)*8+i
//   (k in [48,64) zero-padded), n = nt*16+(lane&15).  8192 halves per array.
// w2f layout: [kt(4)][lane(64)][i(8)], k = kt*32+(lane>>4)*8+i, n = lane&15.
__global__ __launch_bounds__(256) void wpack_kernel(
    const float* __restrict__ w1, const float* __restrict__ w2,
    _Float16* __restrict__ w1fh, _Float16* __restrict__ w1fl,
    _Float16* __restrict__ w2fh, _Float16* __restrict__ w2fl) {
  int t = blockIdx.x * 256 + threadIdx.x;   // 10240 threads
  if (t < 8192) {
    int lane = (t >> 3) & 63, i = t & 7;
    int kt = t >> 12, nt = (t >> 9) & 7;
    int k = kt * 32 + (lane >> 4) * 8 + i;
    int n = nt * 16 + (lane & 15);
    float v = (k < 48) ? w1[n * 48 + k] : 0.f;
    _Float16 h = (_Float16)v;
    w1fh[t] = h;
    w1fl[t] = (_Float16)(v - (float)h);
  } else {
    int u = t - 8192;                        // 2048 threads
    int lane = (u >> 3) & 63, i = u & 7;
    int kt = u >> 9;
    int k = kt * 32 + (lane >> 4) * 8 + i;
    int o = lane & 15;
    float v = w2[o * HIDN + k];
    _Float16 h = (_Float16)v;
    w2fh[u] = h;
    w2fl[u] = (_Float16)(v - (float)h);
  }
}

// MFMA step kernel. 4 waves/block, each wave owns 16 consecutive-x pixels
// end-to-end: perceive -> split-f16 GEMM1 (K=64 pad, N=128) -> relu/split ->
// GEMM2 (K=128, N=16) -> clamp/mask/residual epilogue. All LDS sharing is
// intra-wave (per-wave DS ops are in-order) -> zero barriers. Split-f16
// (hi + lo, drop lo*lo) keeps ~2^-22 relative error == fp32-quality.
__global__ __launch_bounds__(256) void step_mfma(
    const float* __restrict__ s,
    const f16x8* __restrict__ w1fh, const f16x8* __restrict__ w1fl,
    const f16x8* __restrict__ w2fh, const f16x8* __restrict__ w2fl,
    const float* __restrict__ bias1, const float* __restrict__ bias2,
    const unsigned* __restrict__ mask,
    float* __restrict__ mid,
    float* __restrict__ mid3c,
    unsigned char* __restrict__ pre) {
  __shared__ __align__(16) char smem[4 * WREG];
  const int tid = threadIdx.x;
  const int wv = tid >> 6;
  const int l  = tid & 63;
  const int p  = l & 15;        // pixel within wave tile / MFMA row-col lane
  const int g  = l >> 4;        // lane group (k-group for A/B frags)
  char* wb = smem + wv * WREG;
  _Float16* Phi = (_Float16*)wb;
  _Float16* Plo = (_Float16*)(wb + POFF_LO);
  _Float16* Hhi = (_Float16*)wb;            // overlays P (P dead by then)
  _Float16* Hlo = (_Float16*)(wb + HOFF_LO);
  float*    DXl = (float*)(wb + DXOFF);

  const int pid = blockIdx.x * 64 + wv * 16 + p;
  const int b = pid >> 14;
  const int r = pid & 16383;
  const int y = r >> 7, x = r & 127;

  // Early independent loads (overlap with perceive).
  float bv1[8];
  #pragma unroll
  for (int nt = 0; nt < 8; ++nt) bv1[nt] = bias1[nt * 16 + p];
  const float b2v = bias2[p];

  // Zero-pad P feats 48..63: one 16B chunk per lane covers 2 arrays x 16 rows.
  {
    uint4 z; z.x = 0u; z.y = 0u; z.z = 0u; z.w = 0u;
    _Float16* zb = (l & 32) ? Plo : Phi;
    *(uint4*)(zb + (l & 15) * PSTR + 48 + ((l >> 4) & 1) * 8) = z;
  }

  // ---- perceive: lane handles its pixel x 4 channels ----
  const float* sp0 = s + b * IMG + y * WD + x;
  const bool yu = y > 0, yd = y < HT - 1, xl = x > 0, xr = x < WD - 1;
  float sctr[4];
  float premax = -1e30f;
  #pragma unroll
  for (int cc = 0; cc < 4; ++cc) {
    const int c = g * 4 + cc;
    const float* sc = sp0 + c * PLANE;
    float a11 = sc[0];
    float a00 = (yu && xl) ? sc[-WD - 1] : 0.f;
    float a01 = yu         ? sc[-WD]     : 0.f;
    float a02 = (yu && xr) ? sc[-WD + 1] : 0.f;
    float a10 = xl         ? sc[-1]      : 0.f;
    float a12 = xr         ? sc[1]       : 0.f;
    float a20 = (yd && xl) ? sc[WD - 1]  : 0.f;
    float a21 = yd         ? sc[WD]      : 0.f;
    float a22 = (yd && xr) ? sc[WD + 1]  : 0.f;
    float sx = (a02 - a00) + 2.f * (a12 - a10) + (a22 - a20);
    float sy = (a20 - a00) + 2.f * (a21 - a01) + (a22 - a02);
    sctr[cc] = a11;
    _Float16 h0 = (_Float16)a11;
    _Float16 h1 = (_Float16)sx;
    _Float16 h2 = (_Float16)sy;
    Phi[p * PSTR + c]      = h0;
    Plo[p * PSTR + c]      = (_Float16)(a11 - (float)h0);
    Phi[p * PSTR + 16 + c] = h1;
    Plo[p * PSTR + 16 + c] = (_Float16)(sx - (float)h1);
    Phi[p * PSTR + 32 + c] = h2;
    Plo[p * PSTR + 32 + c] = (_Float16)(sy - (float)h2);
    if (g == 0 && cc == 3) {   // alive channel: pre-update maxpool
      float m0 = fmaxf(fmaxf(a00, a01), fmaxf(a02, a10));
      float m1 = fmaxf(fmaxf(a11, a12), fmaxf(a20, a21));
      premax = fmaxf(fmaxf(m0, m1), a22);
    }
  }

  asm volatile("" ::: "memory");  // P writes before A-frag reads (same wave)

  // A-fragments: row = pixel (lane&15), k = g*8+i (self-consistent with wpack)
  const _Float16* prow = Phi + p * PSTR;
  const _Float16* lrow = Plo + p * PSTR;
  f16x8 ah0 = *(const f16x8*)(prow + g * 8);
  f16x8 ah1 = *(const f16x8*)(prow + 32 + g * 8);
  f16x8 al0 = *(const f16x8*)(lrow + g * 8);
  f16x8 al1 = *(const f16x8*)(lrow + 32 + g * 8);

  // ---- GEMM1: acc[nt] = bias1 + P x W1 (split-f16, drop lo*lo) ----
  f32x4 acc[8];
  #pragma unroll
  for (int nt = 0; nt < 8; ++nt) {
    f32x4 a = {bv1[nt], bv1[nt], bv1[nt], bv1[nt]};
    acc[nt] = a;
  }
  #pragma unroll
  for (int nt = 0; nt < 8; ++nt) {
    f16x8 bh0 = w1fh[nt * 64 + l];
    f16x8 bh1 = w1fh[512 + nt * 64 + l];
    f16x8 bl0 = w1fl[nt * 64 + l];
    f16x8 bl1 = w1fl[512 + nt * 64 + l];
    acc[nt] = __builtin_amdgcn_mfma_f32_16x16x32_f16(ah0, bh0, acc[nt], 0, 0, 0);
    acc[nt] = __builtin_amdgcn_mfma_f32_16x16x32_f16(ah1, bh1, acc[nt], 0, 0, 0);
    acc[nt] = __builtin_amdgcn_mfma_f32_16x16x32_f16(ah0, bl0, acc[nt], 0, 0, 0);
    acc[nt] = __builtin_amdgcn_mfma_f32_16x16x32_f16(ah1, bl1, acc[nt], 0, 0, 0);
    acc[nt] = __builtin_amdgcn_mfma_f32_16x16x32_f16(al0, bh0, acc[nt], 0, 0, 0);
    acc[nt] = __builtin_amdgcn_mfma_f32_16x16x32_f16(al1, bh1, acc[nt], 0, 0, 0);
  }

  // Prefetch GEMM2 B-frags + epilogue mask words (independent of LDS phase).
  f16x8 b2h[4], b2l[4];
  #pragma unroll
  for (int kt = 0; kt < 4; ++kt) {
    b2h[kt] = w2fh[kt * 64 + l];
    b2l[kt] = w2fl[kt * 64 + l];
  }
  unsigned mw[4];
  #pragma unroll
  for (int cc = 0; cc < 4; ++cc)
    mw[cc] = mask[((b * CH + g * 4 + cc) * HT + y) * (WD / 32) + (x >> 5)];

  // ---- H stage: relu + split into LDS (D layout: row=(g*4+q), col=nt*16+p)
  #pragma unroll
  for (int nt = 0; nt < 8; ++nt) {
    #pragma unroll
    for (int q = 0; q < 4; ++q) {
      float h = fmaxf(acc[nt][q], 0.f);
      _Float16 hh = (_Float16)h;
      const int idx = (g * 4 + q) * HSTR + nt * 16 + p;
      Hhi[idx] = hh;
      Hlo[idx] = (_Float16)(h - (float)hh);
    }
  }

  asm volatile("" ::: "memory");  // H writes before GEMM2 A-frag reads

  // ---- GEMM2: dx = bias2 + H x W2; 3 independent 4-MFMA chains ----
  f32x4 accP = {b2v, b2v, b2v, b2v};
  f32x4 accQ = {0.f, 0.f, 0.f, 0.f};
  f32x4 accR = {0.f, 0.f, 0.f, 0.f};
  const _Float16* hrow  = Hhi + p * HSTR;
  const _Float16* hlrow = Hlo + p * HSTR;
  #pragma unroll
  for (int kt = 0; kt < 4; ++kt) {
    f16x8 hA = *(const f16x8*)(hrow  + kt * 32 + g * 8);
    f16x8 lA = *(const f16x8*)(hlrow + kt * 32 + g * 8);
    accP = __builtin_amdgcn_mfma_f32_16x16x32_f16(hA, b2h[kt], accP, 0, 0, 0);
    accQ = __builtin_amdgcn_mfma_f32_16x16x32_f16(hA, b2l[kt], accQ, 0, 0, 0);
    accR = __builtin_amdgcn_mfma_f32_16x16x32_f16(lA, b2h[kt], accR, 0, 0, 0);
  }
  f32x4 acc2 = (accP + accQ) + accR;

  // ---- DX transpose through LDS (row=pixel, col=o) ----
  #pragma unroll
  for (int q = 0; q < 4; ++q)
    DXl[(g * 4 + q) * DSTR + p] = acc2[q];

  asm volatile("" ::: "memory");  // DX writes before reads

  if (g == 0) pre[pid] = (premax > 0.1f) ? 1 : 0;

  // ---- epilogue: same lane->(pixel, 4 channels) mapping as perceive, so
  // the residual s-centers are already in registers; coalesced stores.
  #pragma unroll
  for (int cc = 0; cc < 4; ++cc) {
    const int c = g * 4 + cc;
    float d = DXl[p * DSTR + c];
    d = fminf(fmaxf(d, -5.f), 5.f);
    float v = sctr[cc] + (((mw[cc] >> (x & 31)) & 1u) ? d : 0.f);
    mid[b * IMG + c * PLANE + r] = v;
    if (g == 0 && cc == 3) mid3c[pid] = v;   // ch3 snapshot for fmaskzero
  }
}

// UNCHANGED: post = maxpool3(mid3c) > 0.1; dead pixels zeroed in place.
__global__ __launch_bounds__(256) void fmaskzero_kernel(
    const float* __restrict__ mid3c,
    const unsigned char* __restrict__ pre,
    float* __restrict__ mid) {
  int t = blockIdx.x * 256 + threadIdx.x;   // NPIX
  int b = t >> 14;
  int r = t & 16383;
  int y = r >> 7, x = r & 127;
  const float* m3 = mid3c + b * PLANE;
  float mx = -1e30f;
  #pragma unroll
  for (int dy = -1; dy <= 1; ++dy) {
    int yy = y + dy; if ((unsigned)yy >= HT) continue;
    #pragma unroll
    for (int dxx = -1; dxx <= 1; ++dxx) {
      int xx = x + dxx;
      if ((unsigned)xx < WD) mx = fmaxf(mx, m3[yy * WD + xx]);
    }
  }
  if (!((mx > 0.1f) && pre[t])) {
    float* mp = mid + b * IMG + r;
    #pragma unroll
    for (int c = 0; c < CH; ++c) mp[c * PLANE] = 0.f;
  }
}

// UNCHANGED: final post-alive maxpool + apply pre&post.
__global__ __launch_bounds__(256) void step_b(
    const float* __restrict__ mid,
    const unsigned char* __restrict__ pre,
    float* __restrict__ out) {
  int t = blockIdx.x * 256 + threadIdx.x;   // NPIX threads
  int cq = t >> 15;
  int qid = t & 32767;
  int b = qid >> 12;
  int r = qid & 4095;
  int y = r >> 5;
  int x0 = (r & 31) * 4;
  const float* m3 = mid + b * IMG + 3 * PLANE;

  float col[6];
  #pragma unroll
  for (int j = 0; j < 6; ++j) {
    int xx = x0 - 1 + j;
    float m = -1e30f;
    if ((unsigned)xx < WD) {
      #pragma unroll
      for (int dy = -1; dy <= 1; ++dy) {
        int yy = y + dy;
        if ((unsigned)yy < HT) m = fmaxf(m, m3[yy * WD + xx]);
      }
    }
    col[j] = m;
  }

  const unsigned char* pr = pre + b * PLANE + y * WD + x0;
  float f[4];
  #pragma unroll
  for (int i = 0; i < 4; ++i) {
    float mx = fmaxf(fmaxf(col[i], col[i + 1]), col[i + 2]);
    f[i] = ((mx > 0.1f) && pr[i]) ? 1.f : 0.f;
  }

  #pragma unroll
  for (int cc = 0; cc < 4; ++cc) {
    int c = cq * 4 + cc;
    const float4 v = *(const float4*)&mid[b * IMG + c * PLANE + y * WD + x0];
    float4 w;
    w.x = v.x * f[0]; w.y = v.y * f[1]; w.z = v.z * f[2]; w.w = v.w * f[3];
    *(float4*)&out[b * IMG + c * PLANE + y * WD + x0] = w;
  }
}

extern "C" void kernel_launch(void* const* d_in, const int* in_sizes, int n_in,
                              void* d_out, int out_size, void* d_ws, size_t ws_size,
                              hipStream_t stream) {
  const float* x  = (const float*)d_in[0];
  const float* w1 = (const float*)d_in[1];
  const float* b1 = (const float*)d_in[2];
  const float* w2 = (const float*)d_in[3];
  const float* b2 = (const float*)d_in[4];
  float* out = (float*)d_out;

  char* ws = (char*)d_ws;
  float* midbuf[2];
  midbuf[0] = (float*)ws;
  midbuf[1] = (float*)(ws + (size_t)NELEM * 4);
  float* mid3c = (float*)(ws + 2 * (size_t)NELEM * 4);
  unsigned char* pre = (unsigned char*)(ws + 2 * (size_t)NELEM * 4
                                           + (size_t)NPIX * 4);
  unsigned* mask = (unsigned*)(ws + 2 * (size_t)NELEM * 4
                                  + (size_t)NPIX * 4 + NPIX);
  _Float16* w1fh = (_Float16*)(ws + 2 * (size_t)NELEM * 4 + (size_t)NPIX * 4
                                  + NPIX + (size_t)NSTEPS * WORDS_PER_STEP * 4);
  _Float16* w1fl = w1fh + 8192;
  _Float16* w2fh = w1fl + 8192;
  _Float16* w2fl = w2fh + 2048;

  // keys = jax.random.split(key(42), 8): keys[j] = threefry2x32((0,42),(0,j))
  Keys keys;
  for (int j = 0; j < NSTEPS; ++j) {
    unsigned a, b;
    tf2x32(0u, 42u, 0u, (unsigned)j, a, b);
    keys.k[2 * j] = a; keys.k[2 * j + 1] = b;
  }

  mask_kernel<<<(NSTEPS * WORDS_PER_STEP) / 256, 256, 0, stream>>>(mask, keys);
  wpack_kernel<<<40, 256, 0, stream>>>(w1, w2, w1fh, w1fl, w2fh, w2fl);

  for (int s = 0; s < NSTEPS; ++s) {
    const float* src = (s == 0) ? x : midbuf[(s - 1) & 1];
    step_mfma<<<NPIX / 64, 256, 0, stream>>>(
        src,
        (const f16x8*)w1fh, (const f16x8*)w1fl,
        (const f16x8*)w2fh, (const f16x8*)w2fl,
        b1, b2, mask + s * WORDS_PER_STEP,
        midbuf[s & 1], mid3c, pre);
    if (s < NSTEPS - 1)
      fmaskzero_kernel<<<NPIX / 256, 256, 0, stream>>>(
          mid3c, pre, midbuf[s & 1]);
  }
  step_b<<<NPIX / 256, 256, 0, stream>>>(
      midbuf[(NSTEPS - 1) & 1], pre, out);
}